// Round 1
// baseline (527.734 us; speedup 1.0000x reference)
//
#include <hip/hip_runtime.h>

#define N_NODES 8192
#define DIM 128

typedef short bf16x8 __attribute__((ext_vector_type(8)));
typedef float f32x4 __attribute__((ext_vector_type(4)));

__device__ __forceinline__ unsigned short f2bf_rne(float x) {
    unsigned int u = __builtin_bit_cast(unsigned int, x);
    u += 0x7fffu + ((u >> 16) & 1u);   // round-to-nearest-even
    return (unsigned short)(u >> 16);
}
__device__ __forceinline__ float bf2f(unsigned short h) {
    unsigned int u = ((unsigned int)h) << 16;
    return __builtin_bit_cast(float, u);
}

// ---------------- K1: d = rsqrt(rowsum(A) + 1) --------------------------
__global__ __launch_bounds__(256) void k_rowsum(const float* __restrict__ A,
                                                float* __restrict__ d) {
    int row = blockIdx.x;
    const float4* Ar = (const float4*)(A + (size_t)row * N_NODES);
    int t = threadIdx.x;
    float s = 0.f;
#pragma unroll
    for (int i = 0; i < 8; ++i) {
        float4 v = Ar[t + i * 256];
        s += (v.x + v.y) + (v.z + v.w);
    }
#pragma unroll
    for (int off = 32; off > 0; off >>= 1)
        s += __shfl_down(s, off, 64);
    __shared__ float wsum[4];
    if ((t & 63) == 0) wsum[t >> 6] = s;
    __syncthreads();
    if (t == 0) {
        float tot = wsum[0] + wsum[1] + wsum[2] + wsum[3] + 1.0f;  // +I diag
        d[row] = rsqrtf(tot);
    }
}

// ---------------- K2: Zt = bf16( diag(d) * X * W^T ) transposed ---------
// Zt[col][row], col=0..127 (output feature), row=0..8191 (node)
__global__ __launch_bounds__(256) void k_zgemm(const float* __restrict__ X,
                                               const float* __restrict__ W,
                                               const float* __restrict__ d,
                                               unsigned short* __restrict__ Zt) {
    __shared__ float Xs[64][129];
    __shared__ float Ws[64][129];
    int rb = blockIdx.x >> 1;
    int cb = blockIdx.x & 1;
    int t = threadIdx.x;
    const float4* Xg = (const float4*)(X + (size_t)rb * 64 * DIM);
    const float4* Wg = (const float4*)(W + (size_t)cb * 64 * DIM);
#pragma unroll
    for (int i = 0; i < 8; ++i) {
        int f = t + i * 256;
        int r = f >> 5;
        int c = (f & 31) << 2;
        float4 v = Xg[f];
        Xs[r][c] = v.x; Xs[r][c + 1] = v.y; Xs[r][c + 2] = v.z; Xs[r][c + 3] = v.w;
        float4 w = Wg[f];
        Ws[r][c] = w.x; Ws[r][c + 1] = w.y; Ws[r][c + 2] = w.z; Ws[r][c + 3] = w.w;
    }
    __syncthreads();
    int tx = t & 15, ty = t >> 4;
    float acc[4][4] = {};
    for (int k = 0; k < DIM; ++k) {
        float xr[4], wr[4];
#pragma unroll
        for (int i = 0; i < 4; ++i) xr[i] = Xs[ty * 4 + i][k];
#pragma unroll
        for (int j = 0; j < 4; ++j) wr[j] = Ws[tx * 4 + j][k];
#pragma unroll
        for (int i = 0; i < 4; ++i)
#pragma unroll
            for (int j = 0; j < 4; ++j)
                acc[i][j] += xr[i] * wr[j];
    }
#pragma unroll
    for (int i = 0; i < 4; ++i) {
        int row = rb * 64 + ty * 4 + i;
        float dv = d[row];
#pragma unroll
        for (int j = 0; j < 4; ++j) {
            int col = cb * 64 + tx * 4 + j;
            Zt[(size_t)col * N_NODES + row] = f2bf_rne(dv * acc[i][j]);
        }
    }
}

// ---------------- K3: out = diag(d) * ((A+I) @ Z) + b -------------------
// Split-K x4 within a 256-thread block: 4 waves each accumulate a 2048-wide
// K-slice of the same 16-row output tile, then reduce through padded LDS.
// 2048 waves total -> 8 waves/CU (vs 2 before): hides HBM/L2 load latency.
__global__ __launch_bounds__(256) void k_spmm(const float* __restrict__ A,
                                              const unsigned short* __restrict__ Zt,
                                              const float* __restrict__ d,
                                              const float* __restrict__ bias,
                                              float* __restrict__ out) {
    int t = threadIdx.x;
    int lane = t & 63;
    int wave = t >> 6;                 // 0..3 : K-split index
    int l15 = lane & 15, quad = lane >> 4;
    int row0 = blockIdx.x * 16;
    const int KSPAN = N_NODES / 4;     // 2048 per wave
    int kbase = wave * KSPAN;

    // A-fragment base: lane holds A[row0+l15][k + quad*8 + j], j=0..7
    const float* Arow = A + (size_t)(row0 + l15) * N_NODES + quad * 8;
    // B-fragment base: lane holds Z[k + quad*8 + j][n*16 + l15]
    const unsigned short* Zb = Zt + (size_t)l15 * N_NODES + quad * 8;

    f32x4 acc[8];
#pragma unroll
    for (int i = 0; i < 8; ++i) acc[i] = (f32x4){0.f, 0.f, 0.f, 0.f};

#pragma unroll 2
    for (int k = kbase; k < kbase + KSPAN; k += 32) {
        f32x4 a0 = *(const f32x4*)(Arow + k);
        f32x4 a1 = *((const f32x4*)(Arow + k) + 1);
        bf16x8 af;
        af[0] = (short)f2bf_rne(a0[0]); af[1] = (short)f2bf_rne(a0[1]);
        af[2] = (short)f2bf_rne(a0[2]); af[3] = (short)f2bf_rne(a0[3]);
        af[4] = (short)f2bf_rne(a1[0]); af[5] = (short)f2bf_rne(a1[1]);
        af[6] = (short)f2bf_rne(a1[2]); af[7] = (short)f2bf_rne(a1[3]);
        bf16x8 bfr[8];
#pragma unroll
        for (int n = 0; n < 8; ++n)
            bfr[n] = *(const bf16x8*)(Zb + (size_t)n * 16 * N_NODES + k);
#pragma unroll
        for (int n = 0; n < 8; ++n)
            acc[n] = __builtin_amdgcn_mfma_f32_16x16x32_bf16(af, bfr[n], acc[n], 0, 0, 0);
    }

    // ---- cross-wave K reduction through LDS (stride 33 => conflict-free)
    __shared__ float red[4][64][33];
#pragma unroll
    for (int n = 0; n < 8; ++n)
#pragma unroll
        for (int r = 0; r < 4; ++r)
            red[wave][lane][n * 4 + r] = acc[n][r];
    __syncthreads();

    // wave w finishes col-groups {2w, 2w+1}
#pragma unroll
    for (int nn = 0; nn < 2; ++nn) {
        int n = wave * 2 + nn;
        int col = n * 16 + l15;
        float bcol = bias[col];
#pragma unroll
        for (int r = 0; r < 4; ++r) {
            int idx = n * 4 + r;
            float s = red[0][lane][idx] + red[1][lane][idx] +
                      red[2][lane][idx] + red[3][lane][idx];
            int row = row0 + quad * 4 + r;
            float zid = bf2f(Zt[(size_t)col * N_NODES + row]);  // +I term
            out[(size_t)row * DIM + col] = d[row] * (s + zid) + bcol;
        }
    }
}

extern "C" void kernel_launch(void* const* d_in, const int* in_sizes, int n_in,
                              void* d_out, int out_size, void* d_ws, size_t ws_size,
                              hipStream_t stream) {
    const float* X = (const float*)d_in[0];
    const float* A = (const float*)d_in[1];
    const float* W = (const float*)d_in[2];
    const float* b = (const float*)d_in[3];
    float* out = (float*)d_out;

    char* ws = (char*)d_ws;
    float* dinv = (float*)ws;                              // 32 KB
    unsigned short* Zt = (unsigned short*)(ws + 32768);    // 2 MB bf16 [128][8192]

    k_rowsum<<<N_NODES, 256, 0, stream>>>(A, dinv);
    k_zgemm<<<256, 256, 0, stream>>>(X, W, dinv, Zt);
    k_spmm<<<512, 256, 0, stream>>>(A, Zt, dinv, b, out);
}

// Round 2
// 511.417 us; speedup vs baseline: 1.0319x; 1.0319x over previous
//
#include <hip/hip_runtime.h>

#define N_NODES 8192
#define DIM 128

typedef short bf16x8 __attribute__((ext_vector_type(8)));
typedef unsigned short u16x4 __attribute__((ext_vector_type(4)));
typedef float f32x4 __attribute__((ext_vector_type(4)));

__device__ __forceinline__ unsigned short f2bf_rne(float x) {
    unsigned int u = __builtin_bit_cast(unsigned int, x);
    u += 0x7fffu + ((u >> 16) & 1u);   // round-to-nearest-even
    return (unsigned short)(u >> 16);
}
__device__ __forceinline__ float bf2f(unsigned short h) {
    unsigned int u = ((unsigned int)h) << 16;
    return __builtin_bit_cast(float, u);
}

// ---------------- K1: d = rsqrt(rowsum(A) + 1) --------------------------
__global__ __launch_bounds__(256) void k_rowsum(const float* __restrict__ A,
                                                float* __restrict__ d) {
    int row = blockIdx.x;
    const float4* Ar = (const float4*)(A + (size_t)row * N_NODES);
    int t = threadIdx.x;
    float s = 0.f;
#pragma unroll
    for (int i = 0; i < 8; ++i) {
        float4 v = Ar[t + i * 256];
        s += (v.x + v.y) + (v.z + v.w);
    }
#pragma unroll
    for (int off = 32; off > 0; off >>= 1)
        s += __shfl_down(s, off, 64);
    __shared__ float wsum[4];
    if ((t & 63) == 0) wsum[t >> 6] = s;
    __syncthreads();
    if (t == 0) {
        float tot = wsum[0] + wsum[1] + wsum[2] + wsum[3] + 1.0f;  // +I diag
        d[row] = rsqrtf(tot);
    }
}

// ---------------- K2: Zt = bf16( diag(d) * X * W^T ) transposed ---------
// Zt[col][row], col=0..127 (output feature), row=0..8191 (node)
__global__ __launch_bounds__(256) void k_zgemm(const float* __restrict__ X,
                                               const float* __restrict__ W,
                                               const float* __restrict__ d,
                                               unsigned short* __restrict__ Zt) {
    __shared__ float Xs[64][129];
    __shared__ float Ws[64][129];
    int rb = blockIdx.x >> 1;
    int cb = blockIdx.x & 1;
    int t = threadIdx.x;
    const float4* Xg = (const float4*)(X + (size_t)rb * 64 * DIM);
    const float4* Wg = (const float4*)(W + (size_t)cb * 64 * DIM);
#pragma unroll
    for (int i = 0; i < 8; ++i) {
        int f = t + i * 256;
        int r = f >> 5;
        int c = (f & 31) << 2;
        float4 v = Xg[f];
        Xs[r][c] = v.x; Xs[r][c + 1] = v.y; Xs[r][c + 2] = v.z; Xs[r][c + 3] = v.w;
        float4 w = Wg[f];
        Ws[r][c] = w.x; Ws[r][c + 1] = w.y; Ws[r][c + 2] = w.z; Ws[r][c + 3] = w.w;
    }
    __syncthreads();
    int tx = t & 15, ty = t >> 4;
    float acc[4][4] = {};
    for (int k = 0; k < DIM; ++k) {
        float xr[4], wr[4];
#pragma unroll
        for (int i = 0; i < 4; ++i) xr[i] = Xs[ty * 4 + i][k];
#pragma unroll
        for (int j = 0; j < 4; ++j) wr[j] = Ws[tx * 4 + j][k];
#pragma unroll
        for (int i = 0; i < 4; ++i)
#pragma unroll
            for (int j = 0; j < 4; ++j)
                acc[i][j] += xr[i] * wr[j];
    }
#pragma unroll
    for (int i = 0; i < 4; ++i) {
        int row = rb * 64 + ty * 4 + i;
        float dv = d[row];
#pragma unroll
        for (int j = 0; j < 4; ++j) {
            int col = cb * 64 + tx * 4 + j;
            Zt[(size_t)col * N_NODES + row] = f2bf_rne(dv * acc[i][j]);
        }
    }
}

// ---------------- K3: out = diag(d) * ((A+I) @ Z) + b -------------------
// DRAM-locality version: per block, 16 output rows x 128 cols, full K.
// A is staged through LDS in BK=512 chunks: each A row is read as ONE
// contiguous 2KB coalesced burst (good HBM page locality), converted to
// bf16, stored XOR-swizzled ( byte ^= (row&7)<<4 -> uniform bank slots
// for ds_read_b128 fragments). Double-buffered, prefetch-issue-early
// (T14): next chunk's global loads are in flight during current MFMA.
__global__ __launch_bounds__(256) void k_spmm(const float* __restrict__ A,
                                              const unsigned short* __restrict__ Zt,
                                              const float* __restrict__ d,
                                              const float* __restrict__ bias,
                                              float* __restrict__ out) {
    __shared__ unsigned short As[2][16 * 512];   // 2 x 16KB, swizzled bf16
    const int t = threadIdx.x;
    const int lane = t & 63;
    const int wv = t >> 6;                        // 0..3
    const int l15 = lane & 15, quad = lane >> 4;
    const int row0 = blockIdx.x * 16;

    // wave's output col block: [wv*32, wv*32+32)
    const int colb = wv * 32;
    // B-fragment base: lane holds Z[k + quad*8 + j][colb + n*16 + l15]
    const unsigned short* Zb = Zt + (size_t)(colb + l15) * N_NODES + quad * 8;

    f32x4 acc0 = {0.f, 0.f, 0.f, 0.f}, acc1 = {0.f, 0.f, 0.f, 0.f};

    const float* Ag0 = A + (size_t)row0 * N_NODES;

    // ---- prologue: stage chunk 0 (16 rows x 512 f32 -> bf16 LDS)
#pragma unroll
    for (int i = 0; i < 8; ++i) {
        int flat = t + i * 256;
        int r = flat >> 7;                        // 2 rows per 256-thread pass
        int c4 = (flat & 127) << 2;               // f32 col within chunk
        f32x4 v = *(const f32x4*)(Ag0 + (size_t)r * N_NODES + c4);
        int byte = (r * 1024 + c4 * 2) ^ ((r & 7) << 4);
        u16x4 pk = { f2bf_rne(v[0]), f2bf_rne(v[1]), f2bf_rne(v[2]), f2bf_rne(v[3]) };
        *(u16x4*)((char*)As[0] + byte) = pk;
    }
    __syncthreads();

    int cur = 0;
    for (int chunk = 0; chunk < 16; ++chunk) {
        const int kbase = chunk * 512;

        // ---- issue next chunk's global loads FIRST (latency hides under MFMA)
        f32x4 pre0, pre1, pre2, pre3, pre4, pre5, pre6, pre7;
        if (chunk < 15) {
            const float* Ag = Ag0 + kbase + 512;
#define LDPRE(ii, dst)                                                   \
            {   int flat = t + (ii) * 256;                               \
                int r = flat >> 7; int c4 = (flat & 127) << 2;           \
                dst = *(const f32x4*)(Ag + (size_t)r * N_NODES + c4); }
            LDPRE(0, pre0) LDPRE(1, pre1) LDPRE(2, pre2) LDPRE(3, pre3)
            LDPRE(4, pre4) LDPRE(5, pre5) LDPRE(6, pre6) LDPRE(7, pre7)
#undef LDPRE
        }

        // ---- compute current chunk: 16 k-steps of 32
        const char* Ab = (const char*)As[cur];
#pragma unroll
        for (int ks = 0; ks < 16; ++ks) {
            int abyte = (l15 * 1024 + (ks * 32 + quad * 8) * 2) ^ ((l15 & 7) << 4);
            bf16x8 af = *(const bf16x8*)(Ab + abyte);
            bf16x8 b0 = *(const bf16x8*)(Zb + kbase + ks * 32);
            bf16x8 b1 = *(const bf16x8*)(Zb + (size_t)16 * N_NODES + kbase + ks * 32);
            acc0 = __builtin_amdgcn_mfma_f32_16x16x32_bf16(af, b0, acc0, 0, 0, 0);
            acc1 = __builtin_amdgcn_mfma_f32_16x16x32_bf16(af, b1, acc1, 0, 0, 0);
        }

        // ---- convert + write next chunk into the other buffer, flip
        // (single barrier per chunk: write targets the buffer nobody reads)
        if (chunk < 15) {
            unsigned short* Ao = (unsigned short*)As[cur ^ 1];
#define STPRE(ii, src)                                                   \
            {   int flat = t + (ii) * 256;                               \
                int r = flat >> 7; int c4 = (flat & 127) << 2;           \
                int byte = (r * 1024 + c4 * 2) ^ ((r & 7) << 4);         \
                u16x4 pk = { f2bf_rne(src[0]), f2bf_rne(src[1]),         \
                             f2bf_rne(src[2]), f2bf_rne(src[3]) };       \
                *(u16x4*)((char*)Ao + byte) = pk; }
            STPRE(0, pre0) STPRE(1, pre1) STPRE(2, pre2) STPRE(3, pre3)
            STPRE(4, pre4) STPRE(5, pre5) STPRE(6, pre6) STPRE(7, pre7)
#undef STPRE
            __syncthreads();
            cur ^= 1;
        }
    }

    // ---- epilogue: + identity term (Z row), row scale d, bias
#pragma unroll
    for (int n = 0; n < 2; ++n) {
        int col = colb + n * 16 + l15;
        float bcol = bias[col];
        f32x4 a = n ? acc1 : acc0;
#pragma unroll
        for (int r = 0; r < 4; ++r) {
            int row = row0 + quad * 4 + r;
            float zid = bf2f(Zt[(size_t)col * N_NODES + row]);
            out[(size_t)row * DIM + col] = d[row] * (a[r] + zid) + bcol;
        }
    }
}

extern "C" void kernel_launch(void* const* d_in, const int* in_sizes, int n_in,
                              void* d_out, int out_size, void* d_ws, size_t ws_size,
                              hipStream_t stream) {
    const float* X = (const float*)d_in[0];
    const float* A = (const float*)d_in[1];
    const float* W = (const float*)d_in[2];
    const float* b = (const float*)d_in[3];
    float* out = (float*)d_out;

    char* ws = (char*)d_ws;
    float* dinv = (float*)ws;                              // 32 KB
    unsigned short* Zt = (unsigned short*)(ws + 32768);    // 2 MB bf16 [128][8192]

    k_rowsum<<<N_NODES, 256, 0, stream>>>(A, dinv);
    k_zgemm<<<256, 256, 0, stream>>>(X, W, dinv, Zt);
    k_spmm<<<512, 256, 0, stream>>>(A, Zt, dinv, b, out);
}

// Round 3
// 451.666 us; speedup vs baseline: 1.1684x; 1.1323x over previous
//
#include <hip/hip_runtime.h>

#define N_NODES 8192
#define DIM 128

typedef short bf16x8 __attribute__((ext_vector_type(8)));
typedef unsigned short u16x4 __attribute__((ext_vector_type(4)));
typedef float f32x4 __attribute__((ext_vector_type(4)));

__device__ __forceinline__ unsigned short f2bf_rne(float x) {
    unsigned int u = __builtin_bit_cast(unsigned int, x);
    u += 0x7fffu + ((u >> 16) & 1u);   // round-to-nearest-even
    return (unsigned short)(u >> 16);
}
__device__ __forceinline__ float bf2f(unsigned short h) {
    unsigned int u = ((unsigned int)h) << 16;
    return __builtin_bit_cast(float, u);
}

// ---------------- K1: fused rowsum + A -> bf16 fragment-pack ------------
// Block = 16 rows. Streams A coalesced (2KB bursts/row/chunk), computes
// rowsums, converts to bf16, and writes Abp in MFMA A-fragment order:
//   Abp[rb16][kb][lane][j] = bf16(A[rb16*16 + (lane&15)][kb*32 + (lane>>4)*8 + j])
// so k_spmm's A-loads are contiguous 16B/lane wave-loads.
__global__ __launch_bounds__(256) void k_prep(const float* __restrict__ A,
                                              unsigned short* __restrict__ Abp,
                                              float* __restrict__ d) {
    __shared__ unsigned short tile[16 * 512];   // 16KB, XOR-swizzled bf16 chunk
    __shared__ float rs[2][8][128];             // 8KB rowsum partials
    const int t = threadIdx.x;
    const int lane = t & 63, wv = t >> 6;
    const int l15 = lane & 15, quad = lane >> 4;
    const int rb16 = blockIdx.x;
    const float* Ag0 = A + (size_t)rb16 * 16 * N_NODES;
    const int h = t >> 7;              // 0/1: which row parity this thread loads
    const int c4 = (t & 127) << 2;     // f32 col within chunk
    float rsum[8] = {};

    // prologue: chunk 0 loads
    f32x4 pre[8];
#pragma unroll
    for (int i = 0; i < 8; ++i)
        pre[i] = *(const f32x4*)(Ag0 + (size_t)(h + 2 * i) * N_NODES + c4);

    for (int chunk = 0; chunk < 16; ++chunk) {
        f32x4 curv[8];
#pragma unroll
        for (int i = 0; i < 8; ++i) curv[i] = pre[i];
        if (chunk < 15) {
            const float* Ag = Ag0 + (chunk + 1) * 512;
#pragma unroll
            for (int i = 0; i < 8; ++i)
                pre[i] = *(const f32x4*)(Ag + (size_t)(h + 2 * i) * N_NODES + c4);
        }
        __syncthreads();               // prior pack-phase reads of tile done
#pragma unroll
        for (int i = 0; i < 8; ++i) {
            int r = h + 2 * i;
            f32x4 v = curv[i];
            rsum[i] += (v[0] + v[1]) + (v[2] + v[3]);
            int byte = (r * 1024 + c4 * 2) ^ ((r & 7) << 4);
            u16x4 pk = { f2bf_rne(v[0]), f2bf_rne(v[1]), f2bf_rne(v[2]), f2bf_rne(v[3]) };
            *(u16x4*)((char*)tile + byte) = pk;
        }
        __syncthreads();
        // pack phase: wave wv handles 4 k-blocks of this chunk
#pragma unroll
        for (int u = 0; u < 4; ++u) {
            int kk = wv * 4 + u;
            int abyte = (l15 * 1024 + (kk * 32 + quad * 8) * 2) ^ ((l15 & 7) << 4);
            bf16x8 frag = *(const bf16x8*)((const char*)tile + abyte);
            int kbg = chunk * 16 + kk;
            *(bf16x8*)(Abp + ((size_t)(rb16 * 256 + kbg) * 64 + lane) * 8) = frag;
        }
    }

    // rowsum reduction: row r partials live in rsum[r>>1] of threads with h==(r&1)
#pragma unroll
    for (int i = 0; i < 8; ++i) rs[h][i][t & 127] = rsum[i];
    __syncthreads();
    if (t < 16) {
        const float* p = rs[t & 1][t >> 1];
        float s = 0.f;
        for (int j = 0; j < 128; ++j) s += p[j];
        d[rb16 * 16 + t] = rsqrtf(s + 1.0f);   // +1 for the identity diagonal
    }
}

// ---------------- K2: Zp = pack_B( bf16( diag(d) * X * W^T ) ) ----------
// B-fragment order: Zp[kb][c16][lane][j] = Z[kb*32 + (lane>>4)*8 + j][c16*16 + (lane&15)]
__global__ __launch_bounds__(256) void k_zgemm(const float* __restrict__ X,
                                               const float* __restrict__ W,
                                               const float* __restrict__ d,
                                               unsigned short* __restrict__ Zp) {
    __shared__ float Xs[64][129];
    __shared__ float Ws[64][129];
    int rb = blockIdx.x >> 1;
    int cb = blockIdx.x & 1;
    int t = threadIdx.x;
    const float4* Xg = (const float4*)(X + (size_t)rb * 64 * DIM);
    const float4* Wg = (const float4*)(W + (size_t)cb * 64 * DIM);
#pragma unroll
    for (int i = 0; i < 8; ++i) {
        int f = t + i * 256;
        int r = f >> 5;
        int c = (f & 31) << 2;
        float4 v = Xg[f];
        Xs[r][c] = v.x; Xs[r][c + 1] = v.y; Xs[r][c + 2] = v.z; Xs[r][c + 3] = v.w;
        float4 w = Wg[f];
        Ws[r][c] = w.x; Ws[r][c + 1] = w.y; Ws[r][c + 2] = w.z; Ws[r][c + 3] = w.w;
    }
    __syncthreads();
    int tx = t & 15, ty = t >> 4;
    float acc[4][4] = {};
    for (int k = 0; k < DIM; ++k) {
        float xr[4], wr[4];
#pragma unroll
        for (int i = 0; i < 4; ++i) xr[i] = Xs[ty * 4 + i][k];
#pragma unroll
        for (int j = 0; j < 4; ++j) wr[j] = Ws[tx * 4 + j][k];
#pragma unroll
        for (int i = 0; i < 4; ++i)
#pragma unroll
            for (int j = 0; j < 4; ++j)
                acc[i][j] += xr[i] * wr[j];
    }
#pragma unroll
    for (int i = 0; i < 4; ++i) {
        int row = rb * 64 + ty * 4 + i;        // node index (k-dim of spmm)
        float dv = d[row];
        int kb = row >> 5, jj = row & 7;
        int lrow = ((row >> 3) & 3) * 16;
#pragma unroll
        for (int j = 0; j < 4; ++j) {
            int col = cb * 64 + tx * 4 + j;    // feature
            int lanep = lrow + (col & 15);
            Zp[((size_t)(kb * 8 + (col >> 4)) * 64 + lanep) * 8 + jj] =
                f2bf_rne(dv * acc[i][j]);
        }
    }
}

// ---------------- K3: out = diag(d) * ((A+I) @ Z) + b -------------------
// Pure streaming MFMA: every load is a contiguous 16B/lane wave-load from
// the fragment-packed Abp / Zp. 8 waves split K 8 ways (4 waves/SIMD),
// cross-wave reduce through padded LDS.
__global__ __launch_bounds__(512, 4) void k_spmm(const unsigned short* __restrict__ Abp,
                                                 const unsigned short* __restrict__ Zp,
                                                 const float* __restrict__ d,
                                                 const float* __restrict__ bias,
                                                 float* __restrict__ out) {
    const int t = threadIdx.x;
    const int lane = t & 63, wv = t >> 6;      // wv = 0..7 : K-split index
    const int l15 = lane & 15, quad = lane >> 4;
    const int rb16 = blockIdx.x;
    const int row0 = rb16 * 16;

    const unsigned short* Ab = Abp + ((size_t)rb16 * 256 * 64 + lane) * 8;
    const unsigned short* Zb = Zp + (size_t)lane * 8;

    f32x4 acc[8];
#pragma unroll
    for (int c = 0; c < 8; ++c) acc[c] = (f32x4){0.f, 0.f, 0.f, 0.f};

#pragma unroll 2
    for (int kb = wv * 32; kb < wv * 32 + 32; ++kb) {
        bf16x8 af = *(const bf16x8*)(Ab + (size_t)kb * 512);
        const unsigned short* zk = Zb + (size_t)kb * 4096;
#pragma unroll
        for (int c = 0; c < 8; ++c) {
            bf16x8 b = *(const bf16x8*)(zk + c * 512);
            acc[c] = __builtin_amdgcn_mfma_f32_16x16x32_bf16(af, b, acc[c], 0, 0, 0);
        }
    }

    // cross-wave K reduction (stride 33 words -> 2-way-max bank alias, free)
    __shared__ float red[8][64][33];
#pragma unroll
    for (int c = 0; c < 8; ++c)
#pragma unroll
        for (int r = 0; r < 4; ++r)
            red[wv][lane][c * 4 + r] = acc[c][r];
    __syncthreads();

    // wave wv finalizes col-group wv (cols wv*16 .. wv*16+15)
    {
        int col = wv * 16 + l15;
        float bcol = bias[col];
#pragma unroll
        for (int r = 0; r < 4; ++r) {
            int idx = wv * 4 + r;
            float s = 0.f;
#pragma unroll
            for (int w = 0; w < 8; ++w) s += red[w][lane][idx];
            int row = row0 + quad * 4 + r;
            // identity term Z[row][col] gathered from packed Zp
            int kb = row >> 5, jj = row & 7;
            int lanep = ((row >> 3) & 3) * 16 + l15;
            float zid = bf2f(Zp[((size_t)(kb * 8 + wv) * 64 + lanep) * 8 + jj]);
            out[(size_t)row * DIM + col] = d[row] * (s + zid) + bcol;
        }
    }
}

extern "C" void kernel_launch(void* const* d_in, const int* in_sizes, int n_in,
                              void* d_out, int out_size, void* d_ws, size_t ws_size,
                              hipStream_t stream) {
    const float* X = (const float*)d_in[0];
    const float* A = (const float*)d_in[1];
    const float* W = (const float*)d_in[2];
    const float* b = (const float*)d_in[3];
    float* out = (float*)d_out;

    char* ws = (char*)d_ws;
    float* dinv = (float*)ws;                               // 32 KB
    unsigned short* Zp = (unsigned short*)(ws + 32768);     // 2 MB  packed Z
    unsigned short* Abp = (unsigned short*)(ws + 32768 + (2u << 20)); // 128 MB packed A

    k_prep<<<512, 256, 0, stream>>>(A, Abp, dinv);
    k_zgemm<<<256, 256, 0, stream>>>(X, W, dinv, Zp);
    k_spmm<<<512, 512, 0, stream>>>(Abp, Zp, dinv, b, out);
}